// Round 1
// baseline (697.070 us; speedup 1.0000x reference)
//
#include <hip/hip_runtime.h>
#include <hip/hip_bf16.h>

#define NL 3
#define EPS 1e-5f

// ---------------- workspace layout (float offsets) ----------------
#define C_RMSW   0L
#define C_INW    768L
#define C_INB    393984L
#define C_CONVW  397056L
#define C_CONVB  403200L
#define C_XPROJW 404736L
#define C_DTW    466176L
#define C_DTB    478464L
#define C_ALOG   480000L
#define C_DP     504576L
#define C_OUTW   506112L
#define C_OUTB   702720L
#define C_BN1G   703488L
#define C_BN1B   703744L
#define C_W1     704000L
#define C_B1     769536L
#define C_BN2G   769792L
#define C_BN2B   770048L
#define C_W2     770304L
#define C_B2     835840L
#define C_BN3G   836096L
#define C_BN3B   836352L
#define C_W3     836608L
#define C_B3     837120L
#define FLAG_OFF 837184L
#define X0_OFF   837248L
#define X1_OFF   1361536L
#define XZ_OFF   1885824L    // 2 dirs x (4096 x 512)
#define XCT_OFF  6080128L    // 2 dirs x (B,ED,L) e-major conv output (post silu)
#define SZT_OFF  8177280L    // 2 dirs x (B,ED,L) silu(z)
#define DEL_OFF  10274432L   // 2 dirs x (B,ED,L) delta
#define DBC_OFF  12371584L   // 2 dirs x (4096 x 40) [dt8 | B16 | C16]
#define YGT_OFF  12699264L   // 2 dirs x (B,ED,L) gated scan output
#define BNS_OFF  14796416L   // 3 stages x (sc[256], sh[256])
#define H1_OFF   XZ_OFF      // alias: head runs after layers, XZ free
#define H2_OFF   (XZ_OFF + 1048576L)

struct Ptrs { const void* p[25]; };

// convert-job tables: job0/1: x -> X0/X1; jobs 2..25: inputs 1..24
static __device__ const int  CV_SRC[26] = {0,0,1,2,3,4,5,6,7,8,9,10,11,12,13,14,15,16,17,18,19,20,21,22,23,24};
static __device__ const long CV_DST[26] = {X0_OFF,X1_OFF,C_RMSW,C_INW,C_INB,C_CONVW,C_CONVB,C_XPROJW,C_DTW,C_DTB,
                                           C_ALOG,C_DP,C_OUTW,C_OUTB,C_BN1G,C_BN1B,C_W1,C_B1,C_BN2G,C_BN2B,
                                           C_W2,C_B2,C_BN3G,C_BN3B,C_W3,C_B3};
static __device__ const int  CV_SZ[26]  = {524288,524288,768,393216,3072,6144,1536,61440,12288,1536,
                                           24576,1536,196608,768,256,256,65536,256,256,256,
                                           65536,256,256,256,512,2};

__global__ __launch_bounds__(256) void k_convert(Ptrs ps, float* __restrict__ ws) {
  bool isbf = (*(const unsigned int*)ps.p[1]) == 0x3F803F80u;
  if (blockIdx.x == 0 && blockIdx.y == 0 && threadIdx.x == 0) ws[FLAG_OFF] = isbf ? 1.f : 0.f;
  int job = blockIdx.y;
  int n = CV_SZ[job];
  const void* s = ps.p[CV_SRC[job]];
  float* dp = ws + CV_DST[job];
  int stride = gridDim.x * blockDim.x;
  for (int i = blockIdx.x * blockDim.x + threadIdx.x; i < n; i += stride) {
    float v;
    if (isbf) {
      unsigned int u = ((const unsigned short*)s)[i];
      v = __uint_as_float(u << 16);
    } else {
      v = ((const float*)s)[i];
    }
    dp[i] = v;
  }
}

// ---------------- shared GEMM helpers: 64x64 tile, KT=64, LDS ld=68 ----------------
#define ASLD 68

__device__ inline void mm_inner(const float* As, const float* Bs, float4* acc) {
  int tx = threadIdx.x & 15, ty = threadIdx.x >> 4;
  #pragma unroll
  for (int k = 0; k < 64; ++k) {
    float4 av = *(const float4*)&As[k*ASLD + ty*4];
    float4 bv = *(const float4*)&Bs[k*ASLD + tx*4];
    acc[0].x = fmaf(av.x,bv.x,acc[0].x); acc[0].y = fmaf(av.x,bv.y,acc[0].y); acc[0].z = fmaf(av.x,bv.z,acc[0].z); acc[0].w = fmaf(av.x,bv.w,acc[0].w);
    acc[1].x = fmaf(av.y,bv.x,acc[1].x); acc[1].y = fmaf(av.y,bv.y,acc[1].y); acc[1].z = fmaf(av.y,bv.z,acc[1].z); acc[1].w = fmaf(av.y,bv.w,acc[1].w);
    acc[2].x = fmaf(av.z,bv.x,acc[2].x); acc[2].y = fmaf(av.z,bv.y,acc[2].y); acc[2].z = fmaf(av.z,bv.z,acc[2].z); acc[2].w = fmaf(av.z,bv.w,acc[2].w);
    acc[3].x = fmaf(av.w,bv.x,acc[3].x); acc[3].y = fmaf(av.w,bv.y,acc[3].y); acc[3].z = fmaf(av.w,bv.z,acc[3].z); acc[3].w = fmaf(av.w,bv.w,acc[3].w);
  }
}

// stage LDS[k][r] <- src[row0+r][k0+k], rows >= nvalid -> 0 (src row-major, leading dim ld)
__device__ inline void stageT_g(float* S, const float* src, int ld, int row0, int k0, int nvalid) {
  int m = threadIdx.x >> 2, q = threadIdx.x & 3;
  const float* p = src + (long)(row0 + m) * ld + k0 + q*16;
  bool ok = (row0 + m) < nvalid;
  #pragma unroll
  for (int j = 0; j < 4; ++j) {
    float4 v = ok ? *(const float4*)(p + j*4) : make_float4(0.f,0.f,0.f,0.f);
    int kk = q*16 + j*4;
    S[(kk+0)*ASLD+m] = v.x; S[(kk+1)*ASLD+m] = v.y; S[(kk+2)*ASLD+m] = v.z; S[(kk+3)*ASLD+m] = v.w;
  }
}

// stage LDS[k][m] <- srcT[k0+k][m0+m] where srcT is [*, 1024] (already k-major)
__device__ inline void stageD(float* S, const float* srcT, int m0, int k0) {
  int k = threadIdx.x >> 2, q = threadIdx.x & 3;
  const float* p = srcT + (long)(k0 + k) * 1024 + m0 + q*16;
  float4 v0 = *(const float4*)(p);
  float4 v1 = *(const float4*)(p+4);
  float4 v2 = *(const float4*)(p+8);
  float4 v3 = *(const float4*)(p+12);
  float* s = &S[k*ASLD + q*16];
  *(float4*)(s)    = v0; *(float4*)(s+4)  = v1; *(float4*)(s+8)  = v2; *(float4*)(s+12) = v3;
}

// ---------------- K1: RMSNorm + in_proj (M=4096, N=512, K=128) ----------------
__global__ __launch_bounds__(256) void k1_rms_inproj(float* __restrict__ ws, int layer) {
  int d = blockIdx.z, mt = blockIdx.x, nt = blockIdx.y;
  const float* X  = ws + (d ? X1_OFF : X0_OFF);
  const float* W  = ws + C_INW + (long)((d*NL+layer)*512) * 128;
  const float* Rw = ws + C_RMSW + (d*NL+layer)*128;
  const float* Bi = ws + C_INB + (d*NL+layer)*512;
  __shared__ float As[64*ASLD];
  __shared__ float Bs[64*ASLD];
  __shared__ float rsq[64][4];
  __shared__ float rsc[64];
  int tx = threadIdx.x & 15, ty = threadIdx.x >> 4;
  float4 acc[4] = {make_float4(0,0,0,0),make_float4(0,0,0,0),make_float4(0,0,0,0),make_float4(0,0,0,0)};
  float sq = 0.f;
  for (int kt = 0; kt < 2; ++kt) {
    int k0 = kt * 64;
    { // A stage: x * rms_w, track raw sumsq
      int m = threadIdx.x >> 2, q = threadIdx.x & 3;
      const float* p  = X + (long)(mt*64 + m) * 128 + k0 + q*16;
      const float* rw = Rw + k0 + q*16;
      #pragma unroll
      for (int j = 0; j < 4; ++j) {
        float4 v = *(const float4*)(p + j*4);
        float4 r = *(const float4*)(rw + j*4);
        sq += v.x*v.x + v.y*v.y + v.z*v.z + v.w*v.w;
        int kk = q*16 + j*4;
        As[(kk+0)*ASLD+m] = v.x*r.x; As[(kk+1)*ASLD+m] = v.y*r.y;
        As[(kk+2)*ASLD+m] = v.z*r.z; As[(kk+3)*ASLD+m] = v.w*r.w;
      }
    }
    stageT_g(Bs, W, 128, nt*64, k0, 512);
    __syncthreads();
    mm_inner(As, Bs, acc);
    __syncthreads();
  }
  { int m = threadIdx.x >> 2, q = threadIdx.x & 3; rsq[m][q] = sq; }
  __syncthreads();
  if (threadIdx.x < 64) {
    float s = rsq[threadIdx.x][0] + rsq[threadIdx.x][1] + rsq[threadIdx.x][2] + rsq[threadIdx.x][3];
    rsc[threadIdx.x] = rsqrtf(s * (1.f/128.f) + EPS);
  }
  __syncthreads();
  int n0 = nt*64 + tx*4;
  float4 bb = *(const float4*)&Bi[n0];
  float* outp = ws + XZ_OFF + (long)d * 2097152L;
  #pragma unroll
  for (int i = 0; i < 4; ++i) {
    int m = ty*4 + i;
    float r = rsc[m];
    long tok = (long)mt*64 + m;
    float4 v;
    v.x = acc[i].x*r + bb.x; v.y = acc[i].y*r + bb.y;
    v.z = acc[i].z*r + bb.z; v.w = acc[i].w*r + bb.w;
    *(float4*)&outp[tok*512 + n0] = v;
  }
}

// ---------------- K2: depthwise causal conv (dir-aware) + silu, + silu(z); transposed outputs ----------------
__global__ __launch_bounds__(256) void k2_conv(float* __restrict__ ws, int layer) {
  int z = blockIdx.z; int d = z >> 2; int b = z & 3;
  int tt = blockIdx.x;   // 16 tiles of 64 t
  int et = blockIdx.y;   // 4 tiles of 64 e
  const float* xz = ws + XZ_OFF + (long)d * 2097152L + (long)b * 1024 * 512;
  __shared__ float xi[70][ASLD];
  __shared__ float zz[64][ASLD];
  __shared__ float xcT[64][65];
  int t0 = tt * 64;
  int lane = threadIdx.x & 63, r0 = threadIdx.x >> 6;
  for (int r = r0; r < 70; r += 4) {
    int t = t0 - 3 + r;
    float v = 0.f;
    if (t >= 0 && t < 1024) v = xz[(long)t*512 + et*64 + lane];
    xi[r][lane] = v;
  }
  for (int r = r0; r < 64; r += 4) {
    int t = t0 + r;
    zz[r][lane] = xz[(long)t*512 + 256 + et*64 + lane];
  }
  __syncthreads();
  int e = et*64 + lane;
  float4 wv = *(const float4*)(ws + C_CONVW + (long)((d*NL+layer)*256 + e) * 4);
  float cb = ws[C_CONVB + (d*NL+layer)*256 + e];
  for (int r = r0; r < 64; r += 4) {
    float a = cb;
    if (d == 0) a += wv.x*xi[r][lane]   + wv.y*xi[r+1][lane] + wv.z*xi[r+2][lane] + wv.w*xi[r+3][lane];
    else        a += wv.x*xi[r+6][lane] + wv.y*xi[r+5][lane] + wv.z*xi[r+4][lane] + wv.w*xi[r+3][lane];
    float xc = a / (1.f + __expf(-a));
    float zv = zz[r][lane];
    zz[r][lane] = zv / (1.f + __expf(-zv));   // silu(z) in place
    xcT[lane][r] = xc;                        // transposed stash [e][t]
  }
  __syncthreads();
  long ob = (long)(d*4 + b) * 262144L;
  for (int er = r0; er < 64; er += 4) {
    ws[XCT_OFF + ob + (long)(et*64 + er)*1024 + t0 + lane] = xcT[er][lane];
    ws[SZT_OFF + ob + (long)(et*64 + er)*1024 + t0 + lane] = zz[lane][er];
  }
}

// ---------------- K3: xproj GEMM (M=4096, N=40 (padded 64), K=256) ----------------
__global__ __launch_bounds__(256) void k3_xproj(float* __restrict__ ws, int layer) {
  int d = blockIdx.z, mt = blockIdx.x;
  int b = mt >> 4; int m0 = (mt & 15) * 64;
  const float* srcT = ws + XCT_OFF + (long)(d*4 + b) * 262144L;
  const float* W = ws + C_XPROJW + (long)((d*NL+layer)*40) * 256;
  __shared__ float As[64*ASLD];
  __shared__ float Bs[64*ASLD];
  float4 acc[4] = {make_float4(0,0,0,0),make_float4(0,0,0,0),make_float4(0,0,0,0),make_float4(0,0,0,0)};
  for (int kt = 0; kt < 4; ++kt) {
    stageD(As, srcT, m0, kt*64);
    stageT_g(Bs, W, 256, 0, kt*64, 40);
    __syncthreads();
    mm_inner(As, Bs, acc);
    __syncthreads();
  }
  int tx = threadIdx.x & 15, ty = threadIdx.x >> 4;
  int n0 = tx * 4;
  if (n0 < 40) {
    float* outp = ws + DBC_OFF + (long)d * 163840L;
    #pragma unroll
    for (int i = 0; i < 4; ++i) {
      long tok = (long)mt*64 + ty*4 + i;
      *(float4*)&outp[tok*40 + n0] = acc[i];
    }
  }
}

// ---------------- K4: delta = softplus(dt @ dt_w.T + dt_b), transposed write ----------------
__device__ inline float softplusf(float x) {
  if (x > 20.f) return x;
  return __logf(1.f + __expf(x));
}

__global__ __launch_bounds__(256) void k4_dt(float* __restrict__ ws, int layer) {
  int d = blockIdx.z, tc = blockIdx.x, eg = blockIdx.y;
  int lane = threadIdx.x & 63, w = threadIdx.x >> 6;
  int tok = tc*64 + lane;
  int b = tok >> 10, t = tok & 1023;
  int e = eg*4 + w;
  const float* dbc = ws + DBC_OFF + (long)d * 163840L + (long)tok * 40;
  float4 d0 = *(const float4*)(dbc);
  float4 d1 = *(const float4*)(dbc + 4);
  const float* dw = ws + C_DTW + (long)((d*NL+layer)*256 + e) * 8;
  float4 w0 = *(const float4*)(dw);
  float4 w1 = *(const float4*)(dw + 4);
  float a = ws[C_DTB + (d*NL+layer)*256 + e];
  a += d0.x*w0.x + d0.y*w0.y + d0.z*w0.z + d0.w*w0.w
     + d1.x*w1.x + d1.y*w1.y + d1.z*w1.z + d1.w*w1.w;
  ws[DEL_OFF + ((long)(d*4 + b)*256 + e)*1024 + t] = softplusf(a);
}

// ---------------- K5: chunked SSM scan, 16 states/thread, 2-phase ----------------
__global__ __launch_bounds__(256) void k5_scan(float* __restrict__ ws, int layer) {
  int d = blockIdx.z, b = blockIdx.y, e8 = blockIdx.x;
  int tid = threadIdx.x;
  int es = tid >> 5, c = tid & 31;
  int e = e8*8 + es;
  long db_ = (long)(d*4 + b);
  const float* dl = ws + DEL_OFF + (db_*256 + e) * 1024;
  const float* xr = ws + XCT_OFF + (db_*256 + e) * 1024;
  const float* zr = ws + SZT_OFF + (db_*256 + e) * 1024;
  float*       yo = ws + YGT_OFF + (db_*256 + e) * 1024;
  const float* bc = ws + DBC_OFF + (long)d * 163840L + (long)b * 40960L;
  const float* al = ws + C_ALOG + (long)((d*NL+layer)*256 + e) * 16;
  float Dpe = ws[C_DP + (d*NL+layer)*256 + e];
  float An[16]; bool fast = true;
  #pragma unroll
  for (int n = 0; n < 16; ++n) {
    An[n] = -__expf(al[n]);
    fast = fast && (fabsf(An[n] + (float)(n+1)) < 1e-3f * (float)(n+1));
  }
  __shared__ float aL[8*32*17];
  __shared__ float hL[8*32*17];
  float h[16], ap[16];
  #pragma unroll
  for (int n = 0; n < 16; ++n) { h[n] = 0.f; ap[n] = 1.f; }
  // phase A: within-chunk scan from 0; collect (prod a, partial h)
  for (int i = 0; i < 32; ++i) {
    int s = c*32 + i;
    int t = d ? (1023 - s) : s;
    float del = dl[t], xv = xr[t];
    float dx = del * xv;
    const float* bp = bc + (long)t*40 + 8;
    float4 B4[4];
    B4[0] = *(const float4*)(bp);    B4[1] = *(const float4*)(bp+4);
    B4[2] = *(const float4*)(bp+8);  B4[3] = *(const float4*)(bp+12);
    const float* Bv = (const float*)B4;
    if (fast) {
      float q = __expf(-del), p = q;
      #pragma unroll
      for (int n = 0; n < 16; ++n) {
        h[n] = fmaf(p, h[n], dx * Bv[n]);
        ap[n] *= p;
        p *= q;
      }
    } else {
      #pragma unroll
      for (int n = 0; n < 16; ++n) {
        float a = __expf(del * An[n]);
        h[n] = fmaf(a, h[n], dx * Bv[n]);
        ap[n] *= a;
      }
    }
  }
  int base = (es*32 + c) * 17;
  #pragma unroll
  for (int n = 0; n < 16; ++n) { aL[base+n] = ap[n]; hL[base+n] = h[n]; }
  __syncthreads();
  // serial combine over chunks; aL overwritten with h0 per chunk
  if (tid < 128) {
    int e2 = tid >> 4, n = tid & 15;
    float h0 = 0.f;
    for (int cc = 0; cc < 32; ++cc) {
      int ix = (e2*32 + cc)*17 + n;
      float ta = aL[ix], th = hL[ix];
      aL[ix] = h0;
      h0 = fmaf(ta, h0, th);
    }
  }
  __syncthreads();
  #pragma unroll
  for (int n = 0; n < 16; ++n) h[n] = aL[base+n];
  // phase B: rescan with true h0, emit gated y
  for (int i = 0; i < 32; ++i) {
    int s = c*32 + i;
    int t = d ? (1023 - s) : s;
    float del = dl[t], xv = xr[t];
    float dx = del * xv;
    const float* bp = bc + (long)t*40 + 8;
    float4 B4[4], C4[4];
    B4[0] = *(const float4*)(bp);    B4[1] = *(const float4*)(bp+4);
    B4[2] = *(const float4*)(bp+8);  B4[3] = *(const float4*)(bp+12);
    C4[0] = *(const float4*)(bp+16); C4[1] = *(const float4*)(bp+20);
    C4[2] = *(const float4*)(bp+24); C4[3] = *(const float4*)(bp+28);
    const float* Bv = (const float*)B4;
    const float* Cv = (const float*)C4;
    float ya[4] = {0.f, 0.f, 0.f, 0.f};
    if (fast) {
      float q = __expf(-del), p = q;
      #pragma unroll
      for (int n = 0; n < 16; ++n) {
        h[n] = fmaf(p, h[n], dx * Bv[n]);
        ya[n & 3] = fmaf(h[n], Cv[n], ya[n & 3]);
        p *= q;
      }
    } else {
      #pragma unroll
      for (int n = 0; n < 16; ++n) {
        float a = __expf(del * An[n]);
        h[n] = fmaf(a, h[n], dx * Bv[n]);
        ya[n & 3] = fmaf(h[n], Cv[n], ya[n & 3]);
      }
    }
    float y = (ya[0] + ya[1]) + (ya[2] + ya[3]);
    y = fmaf(Dpe, xv, y);
    y *= zr[t];
    yo[t] = y;
  }
}

// ---------------- K6: out_proj GEMM + residual (M=4096, N=128, K=256) ----------------
__global__ __launch_bounds__(256) void k6_outproj(float* __restrict__ ws, int layer) {
  int d = blockIdx.z, mt = blockIdx.x, nt = blockIdx.y;
  int b = mt >> 4; int m0 = (mt & 15) * 64;
  const float* srcT = ws + YGT_OFF + (long)(d*4 + b) * 262144L;
  const float* W  = ws + C_OUTW + (long)((d*NL+layer)*128) * 256;
  const float* Ob = ws + C_OUTB + (d*NL+layer)*128;
  float* Xd = ws + (d ? X1_OFF : X0_OFF);
  __shared__ float As[64*ASLD];
  __shared__ float Bs[64*ASLD];
  float4 acc[4] = {make_float4(0,0,0,0),make_float4(0,0,0,0),make_float4(0,0,0,0),make_float4(0,0,0,0)};
  for (int kt = 0; kt < 4; ++kt) {
    stageD(As, srcT, m0, kt*64);
    stageT_g(Bs, W, 256, nt*64, kt*64, 128);
    __syncthreads();
    mm_inner(As, Bs, acc);
    __syncthreads();
  }
  int tx = threadIdx.x & 15, ty = threadIdx.x >> 4;
  int n0 = nt*64 + tx*4;
  float4 ob4 = *(const float4*)&Ob[n0];
  #pragma unroll
  for (int i = 0; i < 4; ++i) {
    long tok = (long)mt*64 + ty*4 + i;
    float4 cur = *(float4*)&Xd[tok*128 + n0];
    float4 v;
    v.x = acc[i].x + ob4.x + cur.x; v.y = acc[i].y + ob4.y + cur.y;
    v.z = acc[i].z + ob4.z + cur.z; v.w = acc[i].w + ob4.w + cur.w;
    *(float4*)&Xd[tok*128 + n0] = v;
  }
}

// ---------------- BN stats -> folded affine (sc, sh) ----------------
__global__ __launch_bounds__(256) void bn_stats(float* __restrict__ ws, int stage) {
  int ch = blockIdx.x;
  const float* src; long ld; const float* g; const float* bb;
  if (stage == 0) { src = ws + ((ch < 128) ? (X0_OFF + ch) : (X1_OFF + ch - 128)); ld = 128; g = ws + C_BN1G; bb = ws + C_BN1B; }
  else if (stage == 1) { src = ws + H1_OFF + ch; ld = 256; g = ws + C_BN2G; bb = ws + C_BN2B; }
  else { src = ws + H2_OFF + ch; ld = 256; g = ws + C_BN3G; bb = ws + C_BN3B; }
  float s = 0.f, s2 = 0.f;
  for (int i = threadIdx.x; i < 4096; i += 256) {
    float v = src[(long)i * ld];
    s += v; s2 += v*v;
  }
  #pragma unroll
  for (int o = 32; o > 0; o >>= 1) { s += __shfl_down(s, o, 64); s2 += __shfl_down(s2, o, 64); }
  __shared__ float ls[4], ls2[4];
  int wid = threadIdx.x >> 6, lane = threadIdx.x & 63;
  if (lane == 0) { ls[wid] = s; ls2[wid] = s2; }
  __syncthreads();
  if (threadIdx.x == 0) {
    float S = ls[0]+ls[1]+ls[2]+ls[3], S2 = ls2[0]+ls2[1]+ls2[2]+ls2[3];
    float mean = S * (1.f/4096.f);
    float var = S2 * (1.f/4096.f) - mean*mean;
    float sc = g[ch] * rsqrtf(var + EPS);
    ws[BNS_OFF + stage*512 + ch] = sc;
    ws[BNS_OFF + stage*512 + 256 + ch] = bb[ch] - mean * sc;
  }
}

// ---------------- head GEMMs: bn-affine A-stage, bias+leaky epilogue ----------------
template<int STAGE>
__global__ __launch_bounds__(256) void hgemm_k(float* __restrict__ ws, void* dout) {
  int mt = blockIdx.x, nt = blockIdx.y;
  const float* sc = ws + BNS_OFF + STAGE*512;
  const float* sh = sc + 256;
  const float* W = ws + (STAGE == 0 ? C_W1 : (STAGE == 1 ? C_W2 : C_W3));
  __shared__ float As[64*ASLD];
  __shared__ float Bs[64*ASLD];
  float4 acc[4] = {make_float4(0,0,0,0),make_float4(0,0,0,0),make_float4(0,0,0,0),make_float4(0,0,0,0)};
  for (int kt = 0; kt < 4; ++kt) {
    int k0 = kt * 64;
    const float* src; int ld;
    if (STAGE == 0) { ld = 128; src = (k0 < 128) ? (ws + X0_OFF + k0) : (ws + X1_OFF + (k0 - 128)); }
    else { ld = 256; src = ws + (STAGE == 1 ? H1_OFF : H2_OFF) + k0; }
    { // affine A stage
      int m = threadIdx.x >> 2, q = threadIdx.x & 3;
      const float* p   = src + (long)(mt*64 + m) * ld + q*16;
      const float* scp = sc + k0 + q*16;
      const float* shp = sh + k0 + q*16;
      #pragma unroll
      for (int j = 0; j < 4; ++j) {
        float4 v  = *(const float4*)(p + j*4);
        float4 s4 = *(const float4*)(scp + j*4);
        float4 h4 = *(const float4*)(shp + j*4);
        int kk = q*16 + j*4;
        As[(kk+0)*ASLD+m] = v.x*s4.x + h4.x; As[(kk+1)*ASLD+m] = v.y*s4.y + h4.y;
        As[(kk+2)*ASLD+m] = v.z*s4.z + h4.z; As[(kk+3)*ASLD+m] = v.w*s4.w + h4.w;
      }
    }
    stageT_g(Bs, W, 256, nt*64, k0, STAGE == 2 ? 2 : 256);
    __syncthreads();
    mm_inner(As, Bs, acc);
    __syncthreads();
  }
  int tx = threadIdx.x & 15, ty = threadIdx.x >> 4;
  if (STAGE == 2) {
    if (tx == 0) {
      bool isbf = ws[FLAG_OFF] != 0.f;
      float b0 = ws[C_B3], b1 = ws[C_B3 + 1];
      #pragma unroll
      for (int i = 0; i < 4; ++i) {
        long tok = (long)mt*64 + ty*4 + i;
        float v0 = acc[i].x + b0, v1 = acc[i].y + b1;
        if (isbf) {
          __hip_bfloat16* o = (__hip_bfloat16*)dout;
          o[tok*2]   = __float2bfloat16(v0);
          o[tok*2+1] = __float2bfloat16(v1);
        } else {
          float* o = (float*)dout;
          o[tok*2] = v0; o[tok*2+1] = v1;
        }
      }
    }
  } else {
    const float* bp = ws + (STAGE == 0 ? C_B1 : C_B2);
    int n0 = nt*64 + tx*4;
    float4 b4 = *(const float4*)&bp[n0];
    float* H = ws + (STAGE == 0 ? H1_OFF : H2_OFF);
    #pragma unroll
    for (int i = 0; i < 4; ++i) {
      long tok = (long)mt*64 + ty*4 + i;
      float4 v;
      v.x = acc[i].x + b4.x; v.y = acc[i].y + b4.y; v.z = acc[i].z + b4.z; v.w = acc[i].w + b4.w;
      v.x = v.x > 0.f ? v.x : 0.01f*v.x;
      v.y = v.y > 0.f ? v.y : 0.01f*v.y;
      v.z = v.z > 0.f ? v.z : 0.01f*v.z;
      v.w = v.w > 0.f ? v.w : 0.01f*v.w;
      *(float4*)&H[tok*256 + n0] = v;
    }
  }
}

// ---------------- launch ----------------
extern "C" void kernel_launch(void* const* d_in, const int* in_sizes, int n_in,
                              void* d_out, int out_size, void* d_ws, size_t ws_size,
                              hipStream_t stream) {
  (void)in_sizes; (void)n_in; (void)out_size; (void)ws_size;
  float* ws = (float*)d_ws;
  Ptrs ps;
  for (int i = 0; i < 25; ++i) ps.p[i] = d_in[i];
  k_convert<<<dim3(64, 26), dim3(256), 0, stream>>>(ps, ws);
  for (int l = 0; l < NL; ++l) {
    k1_rms_inproj<<<dim3(64, 8, 2), dim3(256), 0, stream>>>(ws, l);
    k2_conv      <<<dim3(16, 4, 8), dim3(256), 0, stream>>>(ws, l);
    k3_xproj     <<<dim3(64, 1, 2), dim3(256), 0, stream>>>(ws, l);
    k4_dt        <<<dim3(64, 64, 2), dim3(256), 0, stream>>>(ws, l);
    k5_scan      <<<dim3(32, 4, 2), dim3(256), 0, stream>>>(ws, l);
    k6_outproj   <<<dim3(64, 2, 2), dim3(256), 0, stream>>>(ws, l);
  }
  bn_stats<<<dim3(256), dim3(256), 0, stream>>>(ws, 0);
  hgemm_k<0><<<dim3(64, 4), dim3(256), 0, stream>>>(ws, d_out);
  bn_stats<<<dim3(256), dim3(256), 0, stream>>>(ws, 1);
  hgemm_k<1><<<dim3(64, 4), dim3(256), 0, stream>>>(ws, d_out);
  bn_stats<<<dim3(256), dim3(256), 0, stream>>>(ws, 2);
  hgemm_k<2><<<dim3(64, 1), dim3(256), 0, stream>>>(ws, d_out);
}

// Round 2
// 463.930 us; speedup vs baseline: 1.5025x; 1.5025x over previous
//
#include <hip/hip_runtime.h>
#include <hip/hip_bf16.h>

#define NL 3
#define EPS 1e-5f

// ---------------- workspace layout (float offsets) ----------------
#define C_RMSW   0L
#define C_INW    768L
#define C_INB    393984L
#define C_CONVW  397056L
#define C_CONVB  403200L
#define C_XPROJW 404736L
#define C_DTW    466176L
#define C_DTB    478464L
#define C_ALOG   480000L
#define C_DP     504576L
#define C_OUTW   506112L
#define C_OUTB   702720L
#define C_BN1G   703488L
#define C_BN1B   703744L
#define C_W1     704000L
#define C_B1     769536L
#define C_BN2G   769792L
#define C_BN2B   770048L
#define C_W2     770304L
#define C_B2     835840L
#define C_BN3G   836096L
#define C_BN3B   836352L
#define C_W3     836608L
#define C_B3     837120L
#define FLAG_OFF 837184L
// token order everywhere below is p-space: p(t) = (t%16)*64 + t/16 within each b-block of 1024
#define X0_OFF   837248L     // [4096 p-rows][128]
#define X1_OFF   1361536L
#define XZT_OFF  1885824L    // 2 dirs x [512 n][4096 p]   (k1 out, transposed)
#define XCP_OFF  6080128L    // 2 dirs x [256 e][4096 p]   (conv+silu out)
#define DBCT_OFF 8177280L    // 2 dirs x [40 n][4096 p]    (xproj out, transposed)
#define YGP_OFF  8504960L    // 2 dirs x [256 e][4096 p]   (gated scan out)
#define BNS_OFF  10602112L   // 3 stages x (sc[256], sh[256])
#define H1_OFF   XZT_OFF     // alias: head runs after layers
#define H2_OFF   (XZT_OFF + 1048576L)

struct Ptrs { const void* p[25]; };

static __device__ const int  CV_SRC[26] = {0,0,1,2,3,4,5,6,7,8,9,10,11,12,13,14,15,16,17,18,19,20,21,22,23,24};
static __device__ const long CV_DST[26] = {X0_OFF,X1_OFF,C_RMSW,C_INW,C_INB,C_CONVW,C_CONVB,C_XPROJW,C_DTW,C_DTB,
                                           C_ALOG,C_DP,C_OUTW,C_OUTB,C_BN1G,C_BN1B,C_W1,C_B1,C_BN2G,C_BN2B,
                                           C_W2,C_B2,C_BN3G,C_BN3B,C_W3,C_B3};
static __device__ const int  CV_SZ[26]  = {524288,524288,768,393216,3072,6144,1536,61440,12288,1536,
                                           24576,1536,196608,768,256,256,65536,256,256,256,
                                           65536,256,256,256,512,2};

__global__ __launch_bounds__(256) void k_convert(Ptrs ps, float* __restrict__ ws) {
  bool isbf = (*(const unsigned int*)ps.p[1]) == 0x3F803F80u;
  if (blockIdx.x == 0 && blockIdx.y == 0 && threadIdx.x == 0) ws[FLAG_OFF] = isbf ? 1.f : 0.f;
  int job = blockIdx.y;
  int n = CV_SZ[job];
  const void* s = ps.p[CV_SRC[job]];
  float* dp = ws + CV_DST[job];
  int stride = gridDim.x * blockDim.x;
  bool permute = (job < 2);
  for (int i = blockIdx.x * blockDim.x + threadIdx.x; i < n; i += stride) {
    long si = i;
    if (permute) {
      int row = i >> 7, col = i & 127;
      int b = row >> 10, p = row & 1023;
      int t = ((p & 63) << 4) + (p >> 6);
      si = ((long)((b << 10) + t) << 7) + col;
    }
    float v;
    if (isbf) {
      unsigned int u = ((const unsigned short*)s)[si];
      v = __uint_as_float(u << 16);
    } else {
      v = ((const float*)s)[si];
    }
    dp[i] = v;
  }
}

// ---------------- shared GEMM helpers: 64x64 tile, KT=64, LDS ld=68 ----------------
#define ASLD 68

__device__ inline void mm_inner(const float* As, const float* Bs, float4* acc) {
  int tx = threadIdx.x & 15, ty = threadIdx.x >> 4;
  #pragma unroll
  for (int k = 0; k < 64; ++k) {
    float4 av = *(const float4*)&As[k*ASLD + ty*4];
    float4 bv = *(const float4*)&Bs[k*ASLD + tx*4];
    acc[0].x = fmaf(av.x,bv.x,acc[0].x); acc[0].y = fmaf(av.x,bv.y,acc[0].y); acc[0].z = fmaf(av.x,bv.z,acc[0].z); acc[0].w = fmaf(av.x,bv.w,acc[0].w);
    acc[1].x = fmaf(av.y,bv.x,acc[1].x); acc[1].y = fmaf(av.y,bv.y,acc[1].y); acc[1].z = fmaf(av.y,bv.z,acc[1].z); acc[1].w = fmaf(av.y,bv.w,acc[1].w);
    acc[2].x = fmaf(av.z,bv.x,acc[2].x); acc[2].y = fmaf(av.z,bv.y,acc[2].y); acc[2].z = fmaf(av.z,bv.z,acc[2].z); acc[2].w = fmaf(av.z,bv.w,acc[2].w);
    acc[3].x = fmaf(av.w,bv.x,acc[3].x); acc[3].y = fmaf(av.w,bv.y,acc[3].y); acc[3].z = fmaf(av.w,bv.z,acc[3].z); acc[3].w = fmaf(av.w,bv.w,acc[3].w);
  }
}

__device__ inline void stageT_g(float* S, const float* src, int ld, int row0, int k0, int nvalid) {
  int m = threadIdx.x >> 2, q = threadIdx.x & 3;
  const float* p = src + (long)(row0 + m) * ld + k0 + q*16;
  bool ok = (row0 + m) < nvalid;
  #pragma unroll
  for (int j = 0; j < 4; ++j) {
    float4 v = ok ? *(const float4*)(p + j*4) : make_float4(0.f,0.f,0.f,0.f);
    int kk = q*16 + j*4;
    S[(kk+0)*ASLD+m] = v.x; S[(kk+1)*ASLD+m] = v.y; S[(kk+2)*ASLD+m] = v.z; S[(kk+3)*ASLD+m] = v.w;
  }
}

// stage LDS[k][m] <- srcT[k0+k][m0+m] where srcT is k-major with leading dim ld
__device__ inline void stageD(float* S, const float* srcT, long ld, int m0, int k0) {
  int k = threadIdx.x >> 2, q = threadIdx.x & 3;
  const float* p = srcT + (long)(k0 + k) * ld + m0 + q*16;
  float4 v0 = *(const float4*)(p);
  float4 v1 = *(const float4*)(p+4);
  float4 v2 = *(const float4*)(p+8);
  float4 v3 = *(const float4*)(p+12);
  float* s = &S[k*ASLD + q*16];
  *(float4*)(s)    = v0; *(float4*)(s+4)  = v1; *(float4*)(s+8)  = v2; *(float4*)(s+12) = v3;
}

// ---------------- K1: RMSNorm + in_proj (M=4096, N=512, K=128), transposed output ----------------
__global__ __launch_bounds__(256) void k1_rms_inproj(float* __restrict__ ws, int layer) {
  int d = blockIdx.z, mt = blockIdx.x, nt = blockIdx.y;
  const float* X  = ws + (d ? X1_OFF : X0_OFF);
  const float* W  = ws + C_INW + (long)((d*NL+layer)*512) * 128;
  const float* Rw = ws + C_RMSW + (d*NL+layer)*128;
  const float* Bi = ws + C_INB + (d*NL+layer)*512;
  __shared__ float As[64*ASLD];
  __shared__ float Bs[64*ASLD];
  __shared__ float rsq[64][4];
  __shared__ float rsc[64];
  int tx = threadIdx.x & 15, ty = threadIdx.x >> 4;
  float4 acc[4] = {make_float4(0,0,0,0),make_float4(0,0,0,0),make_float4(0,0,0,0),make_float4(0,0,0,0)};
  float sq = 0.f;
  for (int kt = 0; kt < 2; ++kt) {
    int k0 = kt * 64;
    {
      int m = threadIdx.x >> 2, q = threadIdx.x & 3;
      const float* p  = X + (long)(mt*64 + m) * 128 + k0 + q*16;
      const float* rw = Rw + k0 + q*16;
      #pragma unroll
      for (int j = 0; j < 4; ++j) {
        float4 v = *(const float4*)(p + j*4);
        float4 r = *(const float4*)(rw + j*4);
        sq += v.x*v.x + v.y*v.y + v.z*v.z + v.w*v.w;
        int kk = q*16 + j*4;
        As[(kk+0)*ASLD+m] = v.x*r.x; As[(kk+1)*ASLD+m] = v.y*r.y;
        As[(kk+2)*ASLD+m] = v.z*r.z; As[(kk+3)*ASLD+m] = v.w*r.w;
      }
    }
    stageT_g(Bs, W, 128, nt*64, k0, 512);
    __syncthreads();
    mm_inner(As, Bs, acc);
    __syncthreads();
  }
  { int m = threadIdx.x >> 2, q = threadIdx.x & 3; rsq[m][q] = sq; }
  __syncthreads();
  if (threadIdx.x < 64) {
    float s = rsq[threadIdx.x][0] + rsq[threadIdx.x][1] + rsq[threadIdx.x][2] + rsq[threadIdx.x][3];
    rsc[threadIdx.x] = rsqrtf(s * (1.f/128.f) + EPS);
  }
  __syncthreads();
  // transpose tile through As (reuse), then write rows of xzT[n][4096]
  int n0 = tx*4;
  float4 bb = *(const float4*)&Bi[nt*64 + n0];
  const float* bbp = (const float*)&bb;
  #pragma unroll
  for (int i = 0; i < 4; ++i) {
    int m = ty*4 + i;
    float r = rsc[m];
    const float* av = (const float*)&acc[i];
    #pragma unroll
    for (int cc = 0; cc < 4; ++cc) {
      As[(n0+cc)*65 + m] = av[cc]*r + bbp[cc];
    }
  }
  __syncthreads();
  float* xzt = ws + XZT_OFF + (long)d*2097152L + (long)(nt*64)*4096 + mt*64;
  #pragma unroll
  for (int r = 0; r < 16; ++r) {
    int el = r*256 + threadIdx.x;
    int row = el >> 6, m = el & 63;
    xzt[(long)row*4096 + m] = As[row*65 + m];
  }
}

// ---------------- K2: depthwise conv + silu, per (d,e) row, p-space in/out ----------------
__global__ __launch_bounds__(256) void k2_conv(float* __restrict__ ws, int layer) {
  int e = blockIdx.x, d = blockIdx.y;
  const float* xrow = ws + XZT_OFF + (long)d*2097152L + (long)e*4096;
  float* orow = ws + XCP_OFF + (long)d*1048576L + (long)e*4096;
  __shared__ float s1[4*1040];  // per b: 16x65 stash, index s(t) = (t%16)*65 + t/16
  __shared__ float s2[4*1040];
  int tid = threadIdx.x;
  #pragma unroll
  for (int r = 0; r < 16; ++r) {
    int g = r*256 + tid;
    int b = g >> 10, p = g & 1023;
    int s = (p >> 6)*65 + (p & 63);   // s(t_of_p(p))
    s1[b*1040 + s] = xrow[g];
  }
  __syncthreads();
  float4 wv = *(const float4*)(ws + C_CONVW + (long)((d*NL+layer)*256 + e) * 4);
  float cb = ws[C_CONVB + (d*NL+layer)*256 + e];
  #pragma unroll
  for (int r = 0; r < 16; ++r) {
    int tg = r*256 + tid;
    int b = tg >> 10, tl = tg & 1023;
    const float* st = s1 + b*1040;
    #define SIDX(t) (((t)&15)*65 + ((t)>>4))
    float a = cb;
    if (d == 0) {
      float x0 = (tl >= 3) ? st[SIDX(tl-3)] : 0.f;
      float x1 = (tl >= 2) ? st[SIDX(tl-2)] : 0.f;
      float x2 = (tl >= 1) ? st[SIDX(tl-1)] : 0.f;
      float x3 = st[SIDX(tl)];
      a += wv.x*x0 + wv.y*x1 + wv.z*x2 + wv.w*x3;
    } else {
      float x0 = (tl <= 1020) ? st[SIDX(tl+3)] : 0.f;
      float x1 = (tl <= 1021) ? st[SIDX(tl+2)] : 0.f;
      float x2 = (tl <= 1022) ? st[SIDX(tl+1)] : 0.f;
      float x3 = st[SIDX(tl)];
      a += wv.x*x0 + wv.y*x1 + wv.z*x2 + wv.w*x3;
    }
    #undef SIDX
    s2[b*1040 + ((tl & 15)*65 + (tl >> 4))] = a / (1.f + __expf(-a));
  }
  __syncthreads();
  #pragma unroll
  for (int r = 0; r < 16; ++r) {
    int g = r*256 + tid;
    int b = g >> 10, p = g & 1023;
    orow[g] = s2[b*1040 + (p >> 6)*65 + (p & 63)];
  }
}

// ---------------- K3: xproj GEMM (M=4096 p, N=40, K=256), transposed output dbcT[40][4096] ----------------
__global__ __launch_bounds__(256) void k3_xproj(float* __restrict__ ws, int layer) {
  int d = blockIdx.z, mt = blockIdx.x;
  int m0 = mt * 64;
  const float* srcT = ws + XCP_OFF + (long)d*1048576L;
  const float* W = ws + C_XPROJW + (long)((d*NL+layer)*40) * 256;
  __shared__ float As[64*ASLD];
  __shared__ float Bs[64*ASLD];
  float4 acc[4] = {make_float4(0,0,0,0),make_float4(0,0,0,0),make_float4(0,0,0,0),make_float4(0,0,0,0)};
  for (int kt = 0; kt < 4; ++kt) {
    stageD(As, srcT, 4096L, m0, kt*64);
    stageT_g(Bs, W, 256, 0, kt*64, 40);
    __syncthreads();
    mm_inner(As, Bs, acc);
    __syncthreads();
  }
  int tx = threadIdx.x & 15, ty = threadIdx.x >> 4;
  #pragma unroll
  for (int i = 0; i < 4; ++i) {
    const float* av = (const float*)&acc[i];
    #pragma unroll
    for (int cc = 0; cc < 4; ++cc) {
      Bs[(tx*4+cc)*65 + ty*4+i] = av[cc];
    }
  }
  __syncthreads();
  float* dbcT = ws + DBCT_OFF + (long)d*163840L;
  #pragma unroll
  for (int r = 0; r < 10; ++r) {
    int el = r*256 + threadIdx.x;
    int n = el >> 6, m = el & 63;
    dbcT[(long)n*4096 + m0 + m] = Bs[n*65 + m];
  }
}

// ---------------- K5: p-space chunked scan (64 chunks x 16 steps), delta + silu(z) inline ----------------
__device__ inline float softplusf(float x) {
  if (x > 20.f) return x;
  return __logf(1.f + __expf(x));
}

__global__ __launch_bounds__(256) void k5_scan(float* __restrict__ ws, int layer) {
  int d = blockIdx.z, b = blockIdx.y, eg = blockIdx.x;
  int es = threadIdx.x >> 6;   // 4 e per block; wave = one e, 64 chunks
  int c  = threadIdx.x & 63;
  int e = eg*4 + es;
  int g0 = b*1024 + c;
  const float* xcp = ws + XCP_OFF + (long)d*1048576L + (long)e*4096 + g0;
  const float* zp  = ws + XZT_OFF + (long)d*2097152L + (long)(256+e)*4096 + g0;
  const float* dbc = ws + DBCT_OFF + (long)d*163840L + g0;   // + n*4096 + i*64
  float*       yo  = ws + YGP_OFF + (long)d*1048576L + (long)e*4096 + g0;
  const float* dw = ws + C_DTW + (long)((d*NL+layer)*256 + e)*8;
  float dtb = ws[C_DTB + (d*NL+layer)*256 + e];
  const float* al = ws + C_ALOG + (long)((d*NL+layer)*256 + e)*16;
  float Dpe = ws[C_DP + (d*NL+layer)*256 + e];
  float dtw[8];
  #pragma unroll
  for (int n = 0; n < 8; ++n) dtw[n] = dw[n];
  float Anv[16]; bool fast = true;
  #pragma unroll
  for (int n = 0; n < 16; ++n) {
    Anv[n] = -__expf(al[n]);
    fast = fast && (fabsf(Anv[n] + (float)(n+1)) < 1e-3f * (float)(n+1));
  }
  __shared__ float aL[4*64*17];
  __shared__ float hL[4*64*17];
  float h[16], ap[16], del[16], xcv[16];
  float Q = 1.f;
  #pragma unroll
  for (int n = 0; n < 16; ++n) { h[n] = 0.f; ap[n] = 1.f; }
  int i0 = d ? 15 : 0, di = d ? -1 : 1;
  // phase A
  for (int s = 0; s < 16; ++s) {
    int i = i0 + s*di;
    int off = i*64;
    float a0 = dtb;
    #pragma unroll
    for (int n = 0; n < 8; ++n) a0 += dbc[(long)n*4096 + off] * dtw[n];
    float dl = softplusf(a0);
    float xc = xcp[off];
    del[s] = dl; xcv[s] = xc;
    float dx = dl * xc;
    if (fast) {
      float q = __expf(-dl);
      float qp[16];
      qp[0]=q; qp[1]=q*q; qp[2]=qp[1]*q; qp[3]=qp[1]*qp[1];
      float q4=qp[3];
      qp[4]=qp[0]*q4; qp[5]=qp[1]*q4; qp[6]=qp[2]*q4; qp[7]=q4*q4;
      float q8=qp[7];
      #pragma unroll
      for (int j = 0; j < 8; ++j) qp[8+j]=qp[j]*q8;
      Q *= q;
      #pragma unroll
      for (int n = 0; n < 16; ++n)
        h[n] = fmaf(qp[n], h[n], dx * dbc[(long)(8+n)*4096 + off]);
    } else {
      #pragma unroll
      for (int n = 0; n < 16; ++n) {
        float a = __expf(dl * Anv[n]);
        ap[n] *= a;
        h[n] = fmaf(a, h[n], dx * dbc[(long)(8+n)*4096 + off]);
      }
    }
  }
  if (fast) {
    float p = Q;
    #pragma unroll
    for (int n = 0; n < 16; ++n) { ap[n] = p; p *= Q; }
  }
  int base = (es*64 + c)*17;
  #pragma unroll
  for (int n = 0; n < 16; ++n) { aL[base+n] = ap[n]; hL[base+n] = h[n]; }
  __syncthreads();
  if (threadIdx.x < 64) {
    int e2 = threadIdx.x >> 4, n = threadIdx.x & 15;
    float h0 = 0.f;
    for (int s2 = 0; s2 < 64; ++s2) {
      int cc = d ? (63 - s2) : s2;
      int ix = (e2*64 + cc)*17 + n;
      float ta = aL[ix], th = hL[ix];
      aL[ix] = h0;
      h0 = fmaf(ta, h0, th);
    }
  }
  __syncthreads();
  #pragma unroll
  for (int n = 0; n < 16; ++n) h[n] = aL[base+n];
  // phase B
  for (int s = 0; s < 16; ++s) {
    int i = i0 + s*di;
    int off = i*64;
    float dl = del[s], xc = xcv[s];
    float dx = dl * xc;
    float zr = zp[off];
    float zg = zr / (1.f + __expf(-zr));
    float ya[4] = {0.f,0.f,0.f,0.f};
    if (fast) {
      float q = __expf(-dl);
      float qp[16];
      qp[0]=q; qp[1]=q*q; qp[2]=qp[1]*q; qp[3]=qp[1]*qp[1];
      float q4=qp[3];
      qp[4]=qp[0]*q4; qp[5]=qp[1]*q4; qp[6]=qp[2]*q4; qp[7]=q4*q4;
      float q8=qp[7];
      #pragma unroll
      for (int j = 0; j < 8; ++j) qp[8+j]=qp[j]*q8;
      #pragma unroll
      for (int n = 0; n < 16; ++n) {
        h[n] = fmaf(qp[n], h[n], dx * dbc[(long)(8+n)*4096 + off]);
        ya[n & 3] = fmaf(h[n], dbc[(long)(24+n)*4096 + off], ya[n & 3]);
      }
    } else {
      #pragma unroll
      for (int n = 0; n < 16; ++n) {
        float a = __expf(dl * Anv[n]);
        h[n] = fmaf(a, h[n], dx * dbc[(long)(8+n)*4096 + off]);
        ya[n & 3] = fmaf(h[n], dbc[(long)(24+n)*4096 + off], ya[n & 3]);
      }
    }
    float y = (ya[0] + ya[1]) + (ya[2] + ya[3]);
    y = fmaf(Dpe, xc, y);
    yo[off] = y * zg;
  }
}

// ---------------- K6: out_proj GEMM + residual (M=4096 p, N=128, K=256) ----------------
__global__ __launch_bounds__(256) void k6_outproj(float* __restrict__ ws, int layer) {
  int d = blockIdx.z, mt = blockIdx.x, nt = blockIdx.y;
  int m0 = mt * 64;
  const float* srcT = ws + YGP_OFF + (long)d*1048576L;
  const float* W  = ws + C_OUTW + (long)((d*NL+layer)*128) * 256;
  const float* Ob = ws + C_OUTB + (d*NL+layer)*128;
  float* Xd = ws + (d ? X1_OFF : X0_OFF);
  __shared__ float As[64*ASLD];
  __shared__ float Bs[64*ASLD];
  float4 acc[4] = {make_float4(0,0,0,0),make_float4(0,0,0,0),make_float4(0,0,0,0),make_float4(0,0,0,0)};
  for (int kt = 0; kt < 4; ++kt) {
    stageD(As, srcT, 4096L, m0, kt*64);
    stageT_g(Bs, W, 256, nt*64, kt*64, 128);
    __syncthreads();
    mm_inner(As, Bs, acc);
    __syncthreads();
  }
  int tx = threadIdx.x & 15, ty = threadIdx.x >> 4;
  int n0 = nt*64 + tx*4;
  float4 ob4 = *(const float4*)&Ob[n0];
  #pragma unroll
  for (int i = 0; i < 4; ++i) {
    long tok = (long)m0 + ty*4 + i;
    float4 cur = *(float4*)&Xd[tok*128 + n0];
    float4 v;
    v.x = acc[i].x + ob4.x + cur.x; v.y = acc[i].y + ob4.y + cur.y;
    v.z = acc[i].z + ob4.z + cur.z; v.w = acc[i].w + ob4.w + cur.w;
    *(float4*)&Xd[tok*128 + n0] = v;
  }
}

// ---------------- BN stats -> folded affine (sc, sh) ----------------
__global__ __launch_bounds__(256) void bn_stats(float* __restrict__ ws, int stage) {
  int ch = blockIdx.x;
  const float* src; long ld; const float* g; const float* bb;
  if (stage == 0) { src = ws + ((ch < 128) ? (X0_OFF + ch) : (X1_OFF + ch - 128)); ld = 128; g = ws + C_BN1G; bb = ws + C_BN1B; }
  else if (stage == 1) { src = ws + H1_OFF + ch; ld = 256; g = ws + C_BN2G; bb = ws + C_BN2B; }
  else { src = ws + H2_OFF + ch; ld = 256; g = ws + C_BN3G; bb = ws + C_BN3B; }
  float s = 0.f, s2 = 0.f;
  for (int i = threadIdx.x; i < 4096; i += 256) {
    float v = src[(long)i * ld];
    s += v; s2 += v*v;
  }
  #pragma unroll
  for (int o = 32; o > 0; o >>= 1) { s += __shfl_down(s, o, 64); s2 += __shfl_down(s2, o, 64); }
  __shared__ float ls[4], ls2[4];
  int wid = threadIdx.x >> 6, lane = threadIdx.x & 63;
  if (lane == 0) { ls[wid] = s; ls2[wid] = s2; }
  __syncthreads();
  if (threadIdx.x == 0) {
    float S = ls[0]+ls[1]+ls[2]+ls[3], S2 = ls2[0]+ls2[1]+ls2[2]+ls2[3];
    float mean = S * (1.f/4096.f);
    float var = S2 * (1.f/4096.f) - mean*mean;
    float sc = g[ch] * rsqrtf(var + EPS);
    ws[BNS_OFF + stage*512 + ch] = sc;
    ws[BNS_OFF + stage*512 + 256 + ch] = bb[ch] - mean * sc;
  }
}

// ---------------- head GEMMs ----------------
template<int STAGE>
__global__ __launch_bounds__(256) void hgemm_k(float* __restrict__ ws, void* dout) {
  int mt = blockIdx.x, nt = blockIdx.y;
  const float* sc = ws + BNS_OFF + STAGE*512;
  const float* sh = sc + 256;
  const float* W = ws + (STAGE == 0 ? C_W1 : (STAGE == 1 ? C_W2 : C_W3));
  __shared__ float As[64*ASLD];
  __shared__ float Bs[64*ASLD];
  float4 acc[4] = {make_float4(0,0,0,0),make_float4(0,0,0,0),make_float4(0,0,0,0),make_float4(0,0,0,0)};
  for (int kt = 0; kt < 4; ++kt) {
    int k0 = kt * 64;
    const float* src; int ld;
    if (STAGE == 0) { ld = 128; src = (k0 < 128) ? (ws + X0_OFF + k0) : (ws + X1_OFF + (k0 - 128)); }
    else { ld = 256; src = ws + (STAGE == 1 ? H1_OFF : H2_OFF) + k0; }
    {
      int m = threadIdx.x >> 2, q = threadIdx.x & 3;
      const float* p   = src + (long)(mt*64 + m) * ld + q*16;
      const float* scp = sc + k0 + q*16;
      const float* shp = sh + k0 + q*16;
      #pragma unroll
      for (int j = 0; j < 4; ++j) {
        float4 v  = *(const float4*)(p + j*4);
        float4 s4 = *(const float4*)(scp + j*4);
        float4 h4 = *(const float4*)(shp + j*4);
        int kk = q*16 + j*4;
        As[(kk+0)*ASLD+m] = v.x*s4.x + h4.x; As[(kk+1)*ASLD+m] = v.y*s4.y + h4.y;
        As[(kk+2)*ASLD+m] = v.z*s4.z + h4.z; As[(kk+3)*ASLD+m] = v.w*s4.w + h4.w;
      }
    }
    stageT_g(Bs, W, 256, nt*64, k0, STAGE == 2 ? 2 : 256);
    __syncthreads();
    mm_inner(As, Bs, acc);
    __syncthreads();
  }
  int tx = threadIdx.x & 15, ty = threadIdx.x >> 4;
  if (STAGE == 2) {
    if (tx == 0) {
      bool isbf = ws[FLAG_OFF] != 0.f;
      float b0 = ws[C_B3], b1 = ws[C_B3 + 1];
      #pragma unroll
      for (int i = 0; i < 4; ++i) {
        int r = mt*64 + ty*4 + i;           // p-space row
        int b = r >> 10, p = r & 1023;
        int t = ((p & 63) << 4) + (p >> 6); // inverse permutation
        long tok = (long)(b << 10) + t;
        float v0 = acc[i].x + b0, v1 = acc[i].y + b1;
        if (isbf) {
          __hip_bfloat16* o = (__hip_bfloat16*)dout;
          o[tok*2]   = __float2bfloat16(v0);
          o[tok*2+1] = __float2bfloat16(v1);
        } else {
          float* o = (float*)dout;
          o[tok*2] = v0; o[tok*2+1] = v1;
        }
      }
    }
  } else {
    const float* bp = ws + (STAGE == 0 ? C_B1 : C_B2);
    int n0 = nt*64 + tx*4;
    float4 b4 = *(const float4*)&bp[n0];
    float* H = ws + (STAGE == 0 ? H1_OFF : H2_OFF);
    #pragma unroll
    for (int i = 0; i < 4; ++i) {
      long tok = (long)mt*64 + ty*4 + i;
      float4 v;
      v.x = acc[i].x + b4.x; v.y = acc[i].y + b4.y; v.z = acc[i].z + b4.z; v.w = acc[i].w + b4.w;
      v.x = v.x > 0.f ? v.x : 0.01f*v.x;
      v.y = v.y > 0.f ? v.y : 0.01f*v.y;
      v.z = v.z > 0.f ? v.z : 0.01f*v.z;
      v.w = v.w > 0.f ? v.w : 0.01f*v.w;
      *(float4*)&H[tok*256 + n0] = v;
    }
  }
}

// ---------------- launch ----------------
extern "C" void kernel_launch(void* const* d_in, const int* in_sizes, int n_in,
                              void* d_out, int out_size, void* d_ws, size_t ws_size,
                              hipStream_t stream) {
  (void)in_sizes; (void)n_in; (void)out_size; (void)ws_size;
  float* ws = (float*)d_ws;
  Ptrs ps;
  for (int i = 0; i < 25; ++i) ps.p[i] = d_in[i];
  k_convert<<<dim3(64, 26), dim3(256), 0, stream>>>(ps, ws);
  for (int l = 0; l < NL; ++l) {
    k1_rms_inproj<<<dim3(64, 8, 2), dim3(256), 0, stream>>>(ws, l);
    k2_conv      <<<dim3(256, 2),   dim3(256), 0, stream>>>(ws, l);
    k3_xproj     <<<dim3(64, 1, 2), dim3(256), 0, stream>>>(ws, l);
    k5_scan      <<<dim3(64, 4, 2), dim3(256), 0, stream>>>(ws, l);
    k6_outproj   <<<dim3(64, 2, 2), dim3(256), 0, stream>>>(ws, l);
  }
  bn_stats<<<dim3(256), dim3(256), 0, stream>>>(ws, 0);
  hgemm_k<0><<<dim3(64, 4), dim3(256), 0, stream>>>(ws, d_out);
  bn_stats<<<dim3(256), dim3(256), 0, stream>>>(ws, 1);
  hgemm_k<1><<<dim3(64, 4), dim3(256), 0, stream>>>(ws, d_out);
  bn_stats<<<dim3(256), dim3(256), 0, stream>>>(ws, 2);
  hgemm_k<2><<<dim3(64, 1), dim3(256), 0, stream>>>(ws, d_out);
}